// Round 9
// baseline (75.177 us; speedup 1.0000x reference)
//
#include <hip/hip_runtime.h>
#include <stdint.h>

#define OUTD 4000
#define NPAD 4096
#define CC 16
#define WW 48
#define HH 48
#define BB 128
#define KD 768          // C*H contraction depth
#define MD 6144         // B*W rows
#define EPSF 1e-6f

#define BM 384          // 8 batches * 48 w
#define BN 128
#define BKU 64          // K elems per pipeline unit (one barrier per unit)
#define UNITS 12        // 768/64
#define SLOT_ELEMS (BM * BKU)          // 24576 elems = 48 KB (A only; B lives in registers)
#define THREADS 512
#define XPB 2304        // blocks for x-conversion in prep_all

using short8 = __attribute__((ext_vector_type(8))) short;
using f32x4  = __attribute__((ext_vector_type(4))) float;

static __device__ __forceinline__ unsigned short f2bf(float f) {
  union { float f; unsigned int u; } v; v.f = f;
  unsigned int u = v.u;
  unsigned int r = (u + 0x7FFFu + ((u >> 16) & 1u)) >> 16;
  return (unsigned short)r;
}

// ---------------- Fused prep: blocks [0,XPB) convert x -> A (bf16, merged (c,h) K axis);
// blocks [XPB, XPB+1024) normalize weights -> Qt (bf16) + wnT (f32, [48][4096]).
__global__ __launch_bounds__(256)
void prep_all(const float* __restrict__ x,
              const float* __restrict__ width,
              const float* __restrict__ height,
              const float* __restrict__ feat,
              unsigned short* __restrict__ A,
              unsigned short* __restrict__ Qt,
              float* __restrict__ wnT) {
  __shared__ float smw[4][WW];
  int bid = blockIdx.x;
  if (bid < XPB) {
    int t = bid * 256 + threadIdx.x;      // XPB*256 == BB*CC*WW*HH/8 exactly
    int e = t * 8;
    int h0 = e % HH;                      // 8 | 48: the 8 elems share (b,c,w)
    int w = (e / HH) % WW;
    int c = (e / (HH * WW)) % CC;
    int b = e / (HH * WW * CC);
    float4 v0 = *(const float4*)(x + e);
    float4 v1 = *(const float4*)(x + e + 4);
    short8 o;
    o[0] = (short)f2bf(v0.x); o[1] = (short)f2bf(v0.y);
    o[2] = (short)f2bf(v0.z); o[3] = (short)f2bf(v0.w);
    o[4] = (short)f2bf(v1.x); o[5] = (short)f2bf(v1.y);
    o[6] = (short)f2bf(v1.z); o[7] = (short)f2bf(v1.w);
    *(short8*)&A[(size_t)(b * WW + w) * KD + c * HH + h0] = o;
  } else {
    int lane = threadIdx.x & 63;
    int wv = threadIdx.x >> 6;            // wave 0..3
    int nbase = (bid - XPB) * 4;
    int n = nbase + wv;                   // 0..4095
    bool valid = (n < OUTD);
    float hv = (valid && lane < HH) ? height[n * HH + lane] : 0.f;
    float wvv = (valid && lane < WW) ? width[n * WW + lane] : 0.f;
    float hs = hv * hv, wsum = wvv * wvv;
    #pragma unroll
    for (int off = 32; off > 0; off >>= 1) {
      hs += __shfl_xor(hs, off);
      wsum += __shfl_xor(wsum, off);
    }
    float hnorm = rsqrtf(hs + EPSF);
    float wnorm = rsqrtf(wsum + EPSF);
    if (lane < WW) smw[wv][lane] = wvv * wnorm;   // 0 for invalid n
    if (valid) {
      #pragma unroll
      for (int i = lane; i < KD; i += 64) {
        int c = i / HH, h = i % HH;
        Qt[(size_t)n * KD + i] = f2bf(feat[n * CC + c] * height[n * HH + h] * hnorm);
      }
    } else {
      #pragma unroll
      for (int i = lane; i < KD; i += 64) Qt[(size_t)n * KD + i] = 0;
    }
    __syncthreads();
    if (threadIdx.x < WW) {
      int w = threadIdx.x;
      float4 o = make_float4(smw[0][w], smw[1][w], smw[2][w], smw[3][w]);
      *(float4*)&wnT[w * NPAD + nbase] = o;
    }
  }
}

// ---------------- Main GEMM: P = A (6144x768) * Qt^T (768x4096), fused w-reduction epilogue.
// 384x128 tile, 8 waves (4m x 2n), wave tile 96x64. Units of BK=64, ONE barrier per unit.
// A staged via global_load_lds into a 2-slot ring (96 KB); B loaded GLOBAL->REG per wave
// (double-buffered, one unit ahead) -- cuts LDS pipe traffic from 224KB to 144KB per unit.
__global__ __launch_bounds__(THREADS, 2)
void gemm_main(const unsigned short* __restrict__ A,   // [6144][768] bf16 bits
               const unsigned short* __restrict__ Qt,  // [4096][768] bf16 bits
               const float* __restrict__ wnT,          // [48][4096]
               const float* __restrict__ bias,         // [4000]
               float* __restrict__ out) {              // [128][4000]
  __shared__ unsigned short S[2 * SLOT_ELEMS];   // 98304 B

  int tid = threadIdx.x;
  int lane = tid & 63;
  int wid = tid >> 6;          // 0..7
  int wm = wid >> 1;           // 0..3 -> 96-row slice of the tile
  int wnh = wid & 1;           // 0..1 -> 64-col half

  // XCD-local mapping: XCD k (= bid&7) owns by in {2k, 2k+1}, sweeps bx.
  int bid = blockIdx.x;        // 0..511
  int xcd = bid & 7;
  int i = bid >> 3;            // 0..63
  int by = xcd * 2 + (i & 1);  // m tile 0..15
  int bx = i >> 1;             // n tile 0..31
  int n0 = bx * BN;
  int m0 = by * BM;

  // ---- A staging: per wave 6 loads per unit (each: 8 rows x 64 elems = 1KB).
  // LDS dest linear; global source granule XOR-pre-swizzled: LDS[row][g*8..] holds
  // global[row][(g ^ (row&7))*8..]  (granule = 8 elems = 16B, row = 128B).
  int rsub = lane >> 3;              // 0..7 row within 8-row chunk
  int cg = lane & 7;                 // granule within 64-elem row
  int gsw = (cg ^ rsub) * 8;
  const unsigned short* gA[6];
  #pragma unroll
  for (int j = 0; j < 6; ++j)
    gA[j] = A + (size_t)(m0 + (wid * 6 + j) * 8 + rsub) * KD + gsw;
  int aD[6];
  #pragma unroll
  for (int j = 0; j < 6; ++j) aD[j] = (wid * 6 + j) * 512;

#define SLOTB(u) (((u) & 1) * SLOT_ELEMS)
#define STAGE_A(u)                                                                  \
  { _Pragma("unroll")                                                               \
    for (int j = 0; j < 6; ++j)                                                     \
      __builtin_amdgcn_global_load_lds(                                             \
          (const __attribute__((address_space(1))) void*)(gA[j] + (u) * BKU),       \
          (__attribute__((address_space(3))) void*)(&S[SLOTB(u) + aD[j]]), 16, 0, 0); }

  // ---- B global->reg: per lane 16B at Qt[(n0+wnh*64+ni*16+q16)*768 + u*64 + kh*32 + hi*8].
  // One wave-load = 16 rows x 64B = 16 full cache lines; re-read by the 4 m-waves -> L1/L2.
  int q16 = lane & 15;
  int hi = lane >> 4;                // 0..3 -> k-granule
  const unsigned short* gQ[4];
  #pragma unroll
  for (int ni = 0; ni < 4; ++ni)
    gQ[ni] = Qt + (size_t)(n0 + wnh * 64 + ni * 16 + q16) * KD + hi * 8;

  short8 bfr[2][8];                  // [set][kh*4+ni]
#define BLOAD(set, u)                                                   \
  { _Pragma("unroll")                                                   \
    for (int kh = 0; kh < 2; ++kh)                                      \
      _Pragma("unroll")                                                 \
      for (int ni = 0; ni < 4; ++ni)                                    \
        bfr[set][kh * 4 + ni] = *(const short8*)&gQ[ni][(u) * BKU + kh * 32]; }

  // ---- A ds_read offsets (elem) with matching swizzle; rows are 64 elems (128B).
  int q7 = q16 & 7;
  int aofs[2];                       // [khalf] base (add mi*16*64)
  #pragma unroll
  for (int kh = 0; kh < 2; ++kh)
    aofs[kh] = (wm * 96 + q16) * BKU + (((kh * 4 + hi) ^ q7) * 8);

  f32x4 acc[6][4] = {};
  short8 afA[6], afB[6];

#define DSREAD_A(afX, u, kh)                                           \
  { const unsigned short* sb = &S[SLOTB(u)];                           \
    _Pragma("unroll")                                                  \
    for (int mi = 0; mi < 6; ++mi)                                     \
      afX[mi] = *(const short8*)&sb[aofs[kh] + mi * 16 * BKU]; }

#define MFMA24(afX, kh, cs)                                            \
  { _Pragma("unroll")                                                  \
    for (int ni = 0; ni < 4; ++ni)                                     \
      _Pragma("unroll")                                                \
      for (int mi = 0; mi < 6; ++mi)                                   \
        acc[mi][ni] = __builtin_amdgcn_mfma_f32_16x16x32_bf16(afX[mi], bfr[cs][(kh) * 4 + ni], acc[mi][ni], 0, 0, 0); }

  // Prologue: stage unit 0 (A) and load unit 0 (B).
  STAGE_A(0);
  BLOAD(0, 0);

  #pragma unroll
  for (int u = 0; u < UNITS; ++u) {
    const int cs = u & 1;
    if (u + 1 < UNITS) {
      STAGE_A(u + 1);                          // 6 vm ops
      BLOAD(cs ^ 1, u + 1);                    // 8 vm ops
      asm volatile("s_waitcnt vmcnt(14)" ::: "memory");   // unit u's A+B landed
    } else {
      asm volatile("s_waitcnt vmcnt(0)" ::: "memory");
    }
    __builtin_amdgcn_s_barrier();              // all waves: A slot u ready
    __builtin_amdgcn_sched_barrier(0);

    DSREAD_A(afA, u, 0);                       // k-half 0 A reads (exposed burst)
    asm volatile("s_waitcnt lgkmcnt(0)" ::: "memory");
    __builtin_amdgcn_sched_barrier(0);
    DSREAD_A(afB, u, 1);                       // k-half 1 A reads: complete under MFMA0
    __builtin_amdgcn_s_setprio(1);
    MFMA24(afA, 0, cs);
    asm volatile("s_waitcnt lgkmcnt(0)" ::: "memory");
    __builtin_amdgcn_sched_barrier(0);
    MFMA24(afB, 1, cs);
    __builtin_amdgcn_s_setprio(0);
    __builtin_amdgcn_sched_barrier(0);
    // no trailing barrier: each wave's slot-u reads are lgkm-drained before its MFMA
    // cluster ends, which precedes barrier(u+1), which precedes STAGE_A(u+2).
  }

  // ---- Epilogue: y[b,n] = sum_w wnT[w][n] * P[(b,w),n] + bias[n]
  // wave rows: wm*96 + mi*16 + hi*4 + rr; batch = by*8 + wm*2 + (mi>=3); w = (mi%3)*16+hi*4+rr.
  int b0 = by * 8 + wm * 2;
  #pragma unroll
  for (int ni = 0; ni < 4; ++ni) {
    int ng = n0 + wnh * 64 + ni * 16 + q16;
    float s0 = 0.f, s1 = 0.f;
    #pragma unroll
    for (int mi = 0; mi < 3; ++mi) {
      int wbase = mi * 16 + hi * 4;
      f32x4 va = acc[mi][ni];
      f32x4 vb = acc[mi + 3][ni];
      #pragma unroll
      for (int r = 0; r < 4; ++r) {
        float t = wnT[(wbase + r) * NPAD + ng];
        s0 += t * va[r];
        s1 += t * vb[r];
      }
    }
    s0 += __shfl_xor(s0, 16); s0 += __shfl_xor(s0, 32);
    s1 += __shfl_xor(s1, 16); s1 += __shfl_xor(s1, 32);
    if (hi == 0 && ng < OUTD) {
      float bv = bias[ng];
      out[(size_t)b0 * OUTD + ng] = s0 + bv;
      out[(size_t)(b0 + 1) * OUTD + ng] = s1 + bv;
    }
  }
#undef STAGE_A
#undef SLOTB
#undef BLOAD
#undef DSREAD_A
#undef MFMA24
}

extern "C" void kernel_launch(void* const* d_in, const int* in_sizes, int n_in,
                              void* d_out, int out_size, void* d_ws, size_t ws_size,
                              hipStream_t stream) {
  const float* x      = (const float*)d_in[0];
  const float* width  = (const float*)d_in[1];
  const float* height = (const float*)d_in[2];
  const float* feat   = (const float*)d_in[3];
  const float* bias   = (const float*)d_in[4];
  float* out = (float*)d_out;

  char* ws = (char*)d_ws;
  unsigned short* A  = (unsigned short*)ws;                        // 6144*768*2 = 9,437,184
  unsigned short* Qt = (unsigned short*)(ws + 9437184);            // 4096*768*2 = 6,291,456
  float* wnT         = (float*)(ws + 9437184 + 6291456);           // 48*4096*4  =   786,432

  prep_all<<<dim3(XPB + NPAD / 4), dim3(256), 0, stream>>>(x, width, height, feat, A, Qt, wnT);
  gemm_main<<<dim3(512), dim3(THREADS), 0, stream>>>(A, Qt, wnT, bias, out);
}